// Round 1
// baseline (1805.863 us; speedup 1.0000x reference)
//
#include <hip/hip_runtime.h>
#include <math.h>

#define Bn 8192
#define Sn 200
#define Fn 128
#define En 64
#define An 64
#define H1n 128
#define H2n 64
#define H3n 32
#define EPSn 1e-5f

// ---------- prep: Wik = Wi @ Wk  [128,64], bk = bi @ Wk [64] ----------
__global__ void din_prep(const float* __restrict__ Wi, const float* __restrict__ bi,
                         const float* __restrict__ Wk,
                         float* __restrict__ wik, float* __restrict__ bk) {
    int idx = blockIdx.x * blockDim.x + threadIdx.x;
    if (idx < Fn * An) {
        int f = idx / An, a = idx % An;
        float s = 0.f;
        for (int e = 0; e < En; ++e) s = fmaf(Wi[f * En + e], Wk[e * An + a], s);
        wik[idx] = s;
    }
    if (idx < An) {
        float s = 0.f;
        for (int e = 0; e < En; ++e) s = fmaf(bi[e], Wk[e * An + idx], s);
        bk[idx] = s;
    }
}

// ---------- main: one block (256 thr = 4 waves) per batch row ----------
__global__ __launch_bounds__(256, 2) void din_main(
    const float* __restrict__ cand, const float* __restrict__ hist,
    const int* __restrict__ hlen,
    const float* __restrict__ Wi, const float* __restrict__ bi,
    const float* __restrict__ Wq, const float* __restrict__ Wv,
    const float* __restrict__ wik, const float* __restrict__ bk,
    const float* __restrict__ W1, const float* __restrict__ b1,
    const float* __restrict__ g1, const float* __restrict__ be1,
    const float* __restrict__ m1, const float* __restrict__ v1,
    const float* __restrict__ W2, const float* __restrict__ b2,
    const float* __restrict__ g2, const float* __restrict__ be2,
    const float* __restrict__ m2, const float* __restrict__ v2,
    const float* __restrict__ W3, const float* __restrict__ b3,
    const float* __restrict__ g3, const float* __restrict__ be3,
    const float* __restrict__ m3, const float* __restrict__ v3,
    const float* __restrict__ Wo, const float* __restrict__ bo,
    float* __restrict__ out)
{
    const int b = blockIdx.x;
    const int tid = threadIdx.x;
    const int wv = tid >> 6;     // wave 0..3
    const int lane = tid & 63;

    __shared__ float s_ce[En];
    __shared__ float s_qhb[An];
    __shared__ float s_m[4], s_d[4];
    __shared__ float s_acc[4][Fn];
    __shared__ float s_sum[4][Fn];
    __shared__ float s_if[Fn];
    __shared__ float s_av[Fn];
    __shared__ float s_x[3 * En];
    __shared__ float s_h1[H1n];
    __shared__ float s_h2[H2n];
    __shared__ float s_h3[H3n];

    // each wave: Wik column for its lane in VGPRs (128 regs)
    float wcol[Fn];
    #pragma unroll
    for (int f = 0; f < Fn; ++f) wcol[f] = wik[f * An + lane];

    // wave 0: candidate embedding ce = cand @ Wi + bi
    if (wv == 0) {
        const float* cr = cand + (size_t)b * Fn;
        float a0 = 0.f, a1 = 0.f, a2 = 0.f, a3 = 0.f;
        #pragma unroll
        for (int f = 0; f < Fn; f += 4) {
            a0 = fmaf(cr[f + 0], Wi[(f + 0) * En + lane], a0);
            a1 = fmaf(cr[f + 1], Wi[(f + 1) * En + lane], a1);
            a2 = fmaf(cr[f + 2], Wi[(f + 2) * En + lane], a2);
            a3 = fmaf(cr[f + 3], Wi[(f + 3) * En + lane], a3);
        }
        s_ce[lane] = (a0 + a1) + (a2 + a3) + bi[lane];
    }
    __syncthreads();
    // wave 0: qhb = ce @ Wq + bk
    if (wv == 0) {
        float a0 = 0.f, a1 = 0.f;
        #pragma unroll
        for (int e = 0; e < En; e += 2) {
            a0 = fmaf(s_ce[e + 0], Wq[(e + 0) * An + lane], a0);
            a1 = fmaf(s_ce[e + 1], Wq[(e + 1) * An + lane], a1);
        }
        s_qhb[lane] = a0 + a1 + bk[lane];
    }
    __syncthreads();

    const int len = hlen[b];
    const float qhb = s_qhb[lane];
    const float wvv = Wv[lane];
    const float* hb = hist + (size_t)b * Sn * Fn;

    float m = -3.0e38f, d = 0.f;
    float2 acc2 = make_float2(0.f, 0.f);
    float2 sum2 = make_float2(0.f, 0.f);

    for (int s = wv; s < len; s += 4) {
        const float* hr = hb + s * Fn;
        // kh[lane] = sum_f h[f] * Wik[f][lane]   (h loads are wave-uniform)
        float k0 = 0.f, k1 = 0.f, k2 = 0.f, k3 = 0.f;
        #pragma unroll
        for (int f = 0; f < Fn; f += 4) {
            k0 = fmaf(hr[f + 0], wcol[f + 0], k0);
            k1 = fmaf(hr[f + 1], wcol[f + 1], k1);
            k2 = fmaf(hr[f + 2], wcol[f + 2], k2);
            k3 = fmaf(hr[f + 3], wcol[f + 3], k3);
        }
        float kh = (k0 + k1) + (k2 + k3);
        float hid = fmaxf(kh + qhb, 0.f);
        float p = hid * wvv;
        #pragma unroll
        for (int o = 32; o > 0; o >>= 1) p += __shfl_xor(p, o, 64);
        // p = score, identical on all lanes
        float2 h2v = ((const float2*)hr)[lane];   // this lane's two F-slots
        float mn = fmaxf(m, p);
        float c = __expf(m - mn);
        float w = __expf(p - mn);
        d = d * c + w;
        acc2.x = fmaf(w, h2v.x, acc2.x * c);
        acc2.y = fmaf(w, h2v.y, acc2.y * c);
        sum2.x += h2v.x;
        sum2.y += h2v.y;
        m = mn;
    }

    if (lane == 0) { s_m[wv] = m; s_d[wv] = d; }
    s_acc[wv][2 * lane + 0] = acc2.x;
    s_acc[wv][2 * lane + 1] = acc2.y;
    s_sum[wv][2 * lane + 0] = sum2.x;
    s_sum[wv][2 * lane + 1] = sum2.y;
    __syncthreads();

    // merge 4 waves' online-softmax state; interest_f and avg_f in F-space
    if (tid < Fn) {
        float M = fmaxf(fmaxf(s_m[0], s_m[1]), fmaxf(s_m[2], s_m[3]));
        float e0 = __expf(s_m[0] - M), e1 = __expf(s_m[1] - M);
        float e2 = __expf(s_m[2] - M), e3 = __expf(s_m[3] - M);
        float D = s_d[0] * e0 + s_d[1] * e1 + s_d[2] * e2 + s_d[3] * e3;
        float A = s_acc[0][tid] * e0 + s_acc[1][tid] * e1 +
                  s_acc[2][tid] * e2 + s_acc[3][tid] * e3;
        float Sm = s_sum[0][tid] + s_sum[1][tid] + s_sum[2][tid] + s_sum[3][tid];
        s_if[tid] = A / D;
        s_av[tid] = Sm / (float)len;
    }
    __syncthreads();

    // project interest_f/avg_f to E-space through Wi (+bi); assemble x[192]
    if (wv == 0) {
        float a0 = 0.f, a1 = 0.f;
        #pragma unroll
        for (int f = 0; f < Fn; f += 2) {
            a0 = fmaf(s_if[f + 0], Wi[(f + 0) * En + lane], a0);
            a1 = fmaf(s_if[f + 1], Wi[(f + 1) * En + lane], a1);
        }
        s_x[lane] = a0 + a1 + bi[lane];
    } else if (wv == 1) {
        float a0 = 0.f, a1 = 0.f;
        #pragma unroll
        for (int f = 0; f < Fn; f += 2) {
            a0 = fmaf(s_av[f + 0], Wi[(f + 0) * En + lane], a0);
            a1 = fmaf(s_av[f + 1], Wi[(f + 1) * En + lane], a1);
        }
        s_x[2 * En + lane] = a0 + a1 + bi[lane];
    } else if (wv == 2) {
        s_x[En + lane] = s_ce[lane];
    }
    __syncthreads();

    // MLP layer 1 (192 -> 128) + BN + relu
    if (tid < H1n) {
        float a0 = 0.f, a1 = 0.f;
        #pragma unroll 8
        for (int j = 0; j < 3 * En; j += 2) {
            a0 = fmaf(s_x[j + 0], W1[(j + 0) * H1n + tid], a0);
            a1 = fmaf(s_x[j + 1], W1[(j + 1) * H1n + tid], a1);
        }
        float acc = a0 + a1 + b1[tid];
        float bn = (acc - m1[tid]) * rsqrtf(v1[tid] + EPSn) * g1[tid] + be1[tid];
        s_h1[tid] = fmaxf(bn, 0.f);
    }
    __syncthreads();
    // layer 2 (128 -> 64)
    if (tid < H2n) {
        float a0 = 0.f, a1 = 0.f;
        #pragma unroll 8
        for (int j = 0; j < H1n; j += 2) {
            a0 = fmaf(s_h1[j + 0], W2[(j + 0) * H2n + tid], a0);
            a1 = fmaf(s_h1[j + 1], W2[(j + 1) * H2n + tid], a1);
        }
        float acc = a0 + a1 + b2[tid];
        float bn = (acc - m2[tid]) * rsqrtf(v2[tid] + EPSn) * g2[tid] + be2[tid];
        s_h2[tid] = fmaxf(bn, 0.f);
    }
    __syncthreads();
    // layer 3 (64 -> 32)
    if (tid < H3n) {
        float a0 = 0.f, a1 = 0.f;
        #pragma unroll 8
        for (int j = 0; j < H2n; j += 2) {
            a0 = fmaf(s_h2[j + 0], W3[(j + 0) * H3n + tid], a0);
            a1 = fmaf(s_h2[j + 1], W3[(j + 1) * H3n + tid], a1);
        }
        float acc = a0 + a1 + b3[tid];
        float bn = (acc - m3[tid]) * rsqrtf(v3[tid] + EPSn) * g3[tid] + be3[tid];
        s_h3[tid] = fmaxf(bn, 0.f);
    }
    __syncthreads();
    // output: logit = h3 @ Wo + bo -> sigmoid
    if (tid == 0) {
        float acc = bo[0];
        for (int j = 0; j < H3n; ++j) acc = fmaf(s_h3[j], Wo[j], acc);
        out[b] = 1.f / (1.f + __expf(-acc));
    }
}

extern "C" void kernel_launch(void* const* d_in, const int* in_sizes, int n_in,
                              void* d_out, int out_size, void* d_ws, size_t ws_size,
                              hipStream_t stream) {
    const float* cand = (const float*)d_in[0];
    const float* hist = (const float*)d_in[1];
    const int*   hlen = (const int*)d_in[2];
    const float* Wi = (const float*)d_in[3];
    const float* bi = (const float*)d_in[4];
    const float* Wq = (const float*)d_in[5];
    const float* Wk = (const float*)d_in[6];
    const float* Wv = (const float*)d_in[7];
    const float* W1 = (const float*)d_in[8];
    const float* b1 = (const float*)d_in[9];
    const float* g1 = (const float*)d_in[10];
    const float* be1 = (const float*)d_in[11];
    const float* m1 = (const float*)d_in[12];
    const float* v1 = (const float*)d_in[13];
    const float* W2 = (const float*)d_in[14];
    const float* b2 = (const float*)d_in[15];
    const float* g2 = (const float*)d_in[16];
    const float* be2 = (const float*)d_in[17];
    const float* m2 = (const float*)d_in[18];
    const float* v2 = (const float*)d_in[19];
    const float* W3 = (const float*)d_in[20];
    const float* b3 = (const float*)d_in[21];
    const float* g3 = (const float*)d_in[22];
    const float* be3 = (const float*)d_in[23];
    const float* m3 = (const float*)d_in[24];
    const float* v3 = (const float*)d_in[25];
    const float* Wo = (const float*)d_in[26];
    const float* bo = (const float*)d_in[27];
    float* out = (float*)d_out;

    float* wik = (float*)d_ws;            // 128*64 floats
    float* bk  = wik + Fn * An;           // 64 floats

    din_prep<<<(Fn * An + 255) / 256, 256, 0, stream>>>(Wi, bi, Wk, wik, bk);
    din_main<<<Bn, 256, 0, stream>>>(cand, hist, hlen, Wi, bi, Wq, Wv, wik, bk,
                                     W1, b1, g1, be1, m1, v1,
                                     W2, b2, g2, be2, m2, v2,
                                     W3, b3, g3, be3, m3, v3,
                                     Wo, bo, out);
}

// Round 2
// 266.647 us; speedup vs baseline: 6.7725x; 6.7725x over previous
//
#include <hip/hip_runtime.h>
#include <math.h>

#define Bn 8192
#define Sn 200
#define Fn 128
#define En 64
#define An 64
#define H1n 128
#define H2n 64
#define H3n 32
#define EPSn 1e-5f
#define CH 64   // chunk rows

typedef __attribute__((ext_vector_type(8))) short bf16x8;
typedef __attribute__((ext_vector_type(4))) float f32x4;

__device__ __forceinline__ uint pack_bf2(float a, float b) {
    uint ua = __float_as_uint(a), ub = __float_as_uint(b);
    ua += 0x7fffu + ((ua >> 16) & 1u);
    ub += 0x7fffu + ((ub >> 16) & 1u);
    return (ua >> 16) | (ub & 0xffff0000u);
}

// ---------- prep: pack Wik = Wi@Wk into per-lane B-fragment order (bf16),
// ---------- plus bk = bi@Wk (fp32). idx = ((ct*4+k)*64 + lane)*8 + j
__global__ void din_prep(const float* __restrict__ Wi, const float* __restrict__ bi,
                         const float* __restrict__ Wk,
                         ushort* __restrict__ wikp, float* __restrict__ bk) {
    int idx = blockIdx.x * blockDim.x + threadIdx.x;   // 0..8191
    int j = idx & 7, l = (idx >> 3) & 63, ctk = idx >> 9;
    int ct = ctk >> 2, k = ctk & 3;
    int kk = k * 32 + 8 * (l >> 4) + j;   // f index (row of Wik)
    int aa = ct * 16 + (l & 15);          // a index (col of Wik)
    float s = 0.f;
    for (int e = 0; e < En; ++e) s = fmaf(Wi[kk * En + e], Wk[e * An + aa], s);
    uint us = __float_as_uint(s); us += 0x7fffu + ((us >> 16) & 1u);
    wikp[idx] = (ushort)(us >> 16);
    if (idx < An) {
        float t = 0.f;
        for (int e = 0; e < En; ++e) t = fmaf(bi[e], Wk[e * An + idx], t);
        bk[idx] = t;
    }
}

// ---------- main: one block (256 thr = 4 waves) per batch row ----------
__global__ __launch_bounds__(256, 4) void din_main(
    const float* __restrict__ cand, const float* __restrict__ hist,
    const int* __restrict__ hlen,
    const float* __restrict__ Wi, const float* __restrict__ bi,
    const float* __restrict__ Wq, const float* __restrict__ Wv,
    const ushort* __restrict__ wikp, const float* __restrict__ bk,
    const float* __restrict__ W1, const float* __restrict__ b1,
    const float* __restrict__ g1, const float* __restrict__ be1,
    const float* __restrict__ m1, const float* __restrict__ v1,
    const float* __restrict__ W2, const float* __restrict__ b2,
    const float* __restrict__ g2, const float* __restrict__ be2,
    const float* __restrict__ m2, const float* __restrict__ v2,
    const float* __restrict__ W3, const float* __restrict__ b3,
    const float* __restrict__ g3, const float* __restrict__ be3,
    const float* __restrict__ m3, const float* __restrict__ v3,
    const float* __restrict__ Wo, const float* __restrict__ bo,
    float* __restrict__ out)
{
    const int b = blockIdx.x;
    const int tid = threadIdx.x;
    const int wv = tid >> 6;
    const int lane = tid & 63;

    __shared__ uint  h_u[CH * 64];      // 16KB: chunk of h, bf16x2 per dword, swizzled
    __shared__ uint  wik_l[4096];       // 16KB: packed B frags, swizzled
    __shared__ float w_sc[CH];          // chunk scores -> weights
    __shared__ float s_ce[En];
    __shared__ float s_qhb[An];
    __shared__ float s_red[4];
    __shared__ float s_accm[4][Fn];
    __shared__ float s_summ[4][Fn];
    __shared__ float s_if[Fn], s_av[Fn];
    __shared__ float s_x[3 * En];
    __shared__ float s_h1[H1n];
    __shared__ float s_h2[H2n];
    __shared__ float s_h3[H3n];

    const int len = hlen[b];

    // stage packed Wik -> LDS (swizzled so frag ds_read_b128 is ~conflict-free)
    {
        const uint4* wp = (const uint4*)wikp;        // 1024 uint4
        for (int q = tid; q < 1024; q += 256) {
            uint4 v = wp[q];
            int l = q & 63;
            int dw = (q * 4) ^ (((l >> 3) & 3) << 2);
            *(uint4*)&wik_l[dw] = v;
        }
    }
    // wave 0: candidate embedding ce = cand@Wi + bi
    if (wv == 0) {
        const float* cr = cand + (size_t)b * Fn;
        float a0 = 0.f, a1 = 0.f, a2 = 0.f, a3 = 0.f;
        #pragma unroll
        for (int f = 0; f < Fn; f += 4) {
            a0 = fmaf(cr[f + 0], Wi[(f + 0) * En + lane], a0);
            a1 = fmaf(cr[f + 1], Wi[(f + 1) * En + lane], a1);
            a2 = fmaf(cr[f + 2], Wi[(f + 2) * En + lane], a2);
            a3 = fmaf(cr[f + 3], Wi[(f + 3) * En + lane], a3);
        }
        s_ce[lane] = (a0 + a1) + (a2 + a3) + bi[lane];
    }
    __syncthreads();
    // wave 0: qhb = ce@Wq + bk
    if (wv == 0) {
        float a0 = 0.f, a1 = 0.f;
        #pragma unroll
        for (int e = 0; e < En; e += 2) {
            a0 = fmaf(s_ce[e + 0], Wq[(e + 0) * An + lane], a0);
            a1 = fmaf(s_ce[e + 1], Wq[(e + 1) * An + lane], a1);
        }
        s_qhb[lane] = a0 + a1 + bk[lane];
    }
    __syncthreads();

    float qhb_l[4], wv_l[4];
    #pragma unroll
    for (int ct = 0; ct < 4; ++ct) {
        qhb_l[ct] = s_qhb[ct * 16 + (lane & 15)];
        wv_l[ct]  = Wv[ct * 16 + (lane & 15)];
    }

    const float* hb = hist + (size_t)b * Sn * Fn;
    float2 acc2 = make_float2(0.f, 0.f), sum2 = make_float2(0.f, 0.f);
    float m = -3.0e38f, d = 0.f;
    const int nch = (len + CH - 1) / CH;

    for (int c = 0; c < nch; ++c) {
        const int sc0 = c * CH;
        // ---- stage chunk: 64 rows x 32 float4 (zero-fill past len)
        for (int i = tid; i < CH * 32; i += 256) {
            int sl = i >> 5, f4 = i & 31;
            int sg = sc0 + sl;
            float4 v = (sg < len) ? ((const float4*)(hb + (size_t)sg * Fn))[f4]
                                  : make_float4(0.f, 0.f, 0.f, 0.f);
            uint2 pw;
            pw.x = pack_bf2(v.x, v.y);
            pw.y = pack_bf2(v.z, v.w);
            int dw = (2 * f4) ^ ((sl & 7) << 2);
            *(uint2*)&h_u[sl * 64 + dw] = pw;
        }
        __syncthreads();
        // ---- scores via MFMA: wave w owns chunk rows [w*16, w*16+16)
        {
            const int r = wv * 16 + (lane & 15);     // A-frag row this lane reads
            float contrib[4] = {0.f, 0.f, 0.f, 0.f};
            #pragma unroll
            for (int ct = 0; ct < 4; ++ct) {
                f32x4 acc = {0.f, 0.f, 0.f, 0.f};
                #pragma unroll
                for (int k = 0; k < 4; ++k) {
                    int dwA = (k * 16 + 4 * (lane >> 4)) ^ ((r & 7) << 2);
                    bf16x8 afr = *(const bf16x8*)&h_u[r * 64 + dwA];
                    int dwB = (((ct * 4 + k) * 64 + lane) * 4) ^ (((lane >> 3) & 3) << 2);
                    bf16x8 bfr = *(const bf16x8*)&wik_l[dwB];
                    acc = __builtin_amdgcn_mfma_f32_16x16x32_bf16(afr, bfr, acc, 0, 0, 0);
                }
                float qv = qhb_l[ct], wvv = wv_l[ct];
                #pragma unroll
                for (int rr = 0; rr < 4; ++rr)
                    contrib[rr] += fmaxf(acc[rr] + qv, 0.f) * wvv;
            }
            // sum over the 16 lanes (different a) holding the same rows
            #pragma unroll
            for (int o = 1; o < 16; o <<= 1) {
                #pragma unroll
                for (int rr = 0; rr < 4; ++rr)
                    contrib[rr] += __shfl_xor(contrib[rr], o, 64);
            }
            if ((lane & 15) == 0) {
                #pragma unroll
                for (int rr = 0; rr < 4; ++rr) {
                    int sl = wv * 16 + (lane >> 4) * 4 + rr;
                    w_sc[sl] = (sc0 + sl < len) ? contrib[rr] : -1e30f;
                }
            }
        }
        __syncthreads();
        // ---- wave0: online softmax over this chunk's 64 scores
        if (wv == 0) {
            float sc = w_sc[lane];
            float mc = sc;
            #pragma unroll
            for (int o = 1; o < 64; o <<= 1) mc = fmaxf(mc, __shfl_xor(mc, o, 64));
            float mn = fmaxf(m, mc);
            float cc = __expf(m - mn);
            float wl = __expf(sc - mn);
            float sm = wl;
            #pragma unroll
            for (int o = 1; o < 64; o <<= 1) sm += __shfl_xor(sm, o, 64);
            d = d * cc + sm;
            m = mn;
            w_sc[lane] = wl;
            if (lane == 0) s_red[0] = cc;
        }
        __syncthreads();
        // ---- pooling: wave w handles s = w (mod 4); lane l -> f-pair l
        {
            float cc = s_red[0];
            acc2.x *= cc; acc2.y *= cc;
            for (int sl = wv; sl < CH; sl += 4) {
                int sg = sc0 + sl;
                if (sg >= len) break;
                float wgt = w_sc[sl];
                uint hv = h_u[sl * 64 + (lane ^ ((sl & 7) << 2))];
                float hx = __uint_as_float(hv << 16);
                float hy = __uint_as_float(hv & 0xffff0000u);
                acc2.x = fmaf(wgt, hx, acc2.x);
                acc2.y = fmaf(wgt, hy, acc2.y);
                sum2.x += hx; sum2.y += hy;
            }
        }
        __syncthreads();    // before next chunk overwrites h_u / w_sc
    }

    if (wv == 0 && lane == 0) s_red[1] = d;
    s_accm[wv][2 * lane + 0] = acc2.x;
    s_accm[wv][2 * lane + 1] = acc2.y;
    s_summ[wv][2 * lane + 0] = sum2.x;
    s_summ[wv][2 * lane + 1] = sum2.y;
    __syncthreads();

    if (tid < Fn) {
        float A  = s_accm[0][tid] + s_accm[1][tid] + s_accm[2][tid] + s_accm[3][tid];
        float Sm = s_summ[0][tid] + s_summ[1][tid] + s_summ[2][tid] + s_summ[3][tid];
        float D = s_red[1];
        s_if[tid] = A / D;
        s_av[tid] = Sm / (float)len;
    }
    __syncthreads();

    // project interest_f/avg_f to E-space through Wi (+bi); assemble x[192]
    if (wv == 0) {
        float a0 = 0.f, a1 = 0.f;
        #pragma unroll
        for (int f = 0; f < Fn; f += 2) {
            a0 = fmaf(s_if[f + 0], Wi[(f + 0) * En + lane], a0);
            a1 = fmaf(s_if[f + 1], Wi[(f + 1) * En + lane], a1);
        }
        s_x[lane] = a0 + a1 + bi[lane];
    } else if (wv == 1) {
        float a0 = 0.f, a1 = 0.f;
        #pragma unroll
        for (int f = 0; f < Fn; f += 2) {
            a0 = fmaf(s_av[f + 0], Wi[(f + 0) * En + lane], a0);
            a1 = fmaf(s_av[f + 1], Wi[(f + 1) * En + lane], a1);
        }
        s_x[2 * En + lane] = a0 + a1 + bi[lane];
    } else if (wv == 2) {
        s_x[En + lane] = s_ce[lane];
    }
    __syncthreads();

    // MLP layer 1 (192 -> 128) + BN + relu
    if (tid < H1n) {
        float a0 = 0.f, a1 = 0.f;
        #pragma unroll 8
        for (int j = 0; j < 3 * En; j += 2) {
            a0 = fmaf(s_x[j + 0], W1[(j + 0) * H1n + tid], a0);
            a1 = fmaf(s_x[j + 1], W1[(j + 1) * H1n + tid], a1);
        }
        float acc = a0 + a1 + b1[tid];
        float bn = (acc - m1[tid]) * rsqrtf(v1[tid] + EPSn) * g1[tid] + be1[tid];
        s_h1[tid] = fmaxf(bn, 0.f);
    }
    __syncthreads();
    if (tid < H2n) {
        float a0 = 0.f, a1 = 0.f;
        #pragma unroll 8
        for (int j = 0; j < H1n; j += 2) {
            a0 = fmaf(s_h1[j + 0], W2[(j + 0) * H2n + tid], a0);
            a1 = fmaf(s_h1[j + 1], W2[(j + 1) * H2n + tid], a1);
        }
        float acc = a0 + a1 + b2[tid];
        float bn = (acc - m2[tid]) * rsqrtf(v2[tid] + EPSn) * g2[tid] + be2[tid];
        s_h2[tid] = fmaxf(bn, 0.f);
    }
    __syncthreads();
    if (tid < H3n) {
        float a0 = 0.f, a1 = 0.f;
        #pragma unroll 8
        for (int j = 0; j < H2n; j += 2) {
            a0 = fmaf(s_h2[j + 0], W3[(j + 0) * H3n + tid], a0);
            a1 = fmaf(s_h2[j + 1], W3[(j + 1) * H3n + tid], a1);
        }
        float acc = a0 + a1 + b3[tid];
        float bn = (acc - m3[tid]) * rsqrtf(v3[tid] + EPSn) * g3[tid] + be3[tid];
        s_h3[tid] = fmaxf(bn, 0.f);
    }
    __syncthreads();
    if (tid == 0) {
        float acc = bo[0];
        for (int j = 0; j < H3n; ++j) acc = fmaf(s_h3[j], Wo[j], acc);
        out[b] = 1.f / (1.f + __expf(-acc));
    }
}

extern "C" void kernel_launch(void* const* d_in, const int* in_sizes, int n_in,
                              void* d_out, int out_size, void* d_ws, size_t ws_size,
                              hipStream_t stream) {
    const float* cand = (const float*)d_in[0];
    const float* hist = (const float*)d_in[1];
    const int*   hlen = (const int*)d_in[2];
    const float* Wi = (const float*)d_in[3];
    const float* bi = (const float*)d_in[4];
    const float* Wq = (const float*)d_in[5];
    const float* Wk = (const float*)d_in[6];
    const float* Wv = (const float*)d_in[7];
    const float* W1 = (const float*)d_in[8];
    const float* b1 = (const float*)d_in[9];
    const float* g1 = (const float*)d_in[10];
    const float* be1 = (const float*)d_in[11];
    const float* m1 = (const float*)d_in[12];
    const float* v1 = (const float*)d_in[13];
    const float* W2 = (const float*)d_in[14];
    const float* b2 = (const float*)d_in[15];
    const float* g2 = (const float*)d_in[16];
    const float* be2 = (const float*)d_in[17];
    const float* m2 = (const float*)d_in[18];
    const float* v2 = (const float*)d_in[19];
    const float* W3 = (const float*)d_in[20];
    const float* b3 = (const float*)d_in[21];
    const float* g3 = (const float*)d_in[22];
    const float* be3 = (const float*)d_in[23];
    const float* m3 = (const float*)d_in[24];
    const float* v3 = (const float*)d_in[25];
    const float* Wo = (const float*)d_in[26];
    const float* bo = (const float*)d_in[27];
    float* out = (float*)d_out;

    ushort* wikp = (ushort*)d_ws;                 // 8192 ushorts = 16KB
    float*  bk   = (float*)((char*)d_ws + 16384); // 64 floats

    din_prep<<<32, 256, 0, stream>>>(Wi, bi, Wk, wikp, bk);
    din_main<<<Bn, 256, 0, stream>>>(cand, hist, hlen, Wi, bi, Wq, Wv, wikp, bk,
                                     W1, b1, g1, be1, m1, v1,
                                     W2, b2, g2, be2, m2, v2,
                                     W3, b3, g3, be3, m3, v3,
                                     Wo, bo, out);
}